// Round 1
// 483.874 us; speedup vs baseline: 1.1471x; 1.1471x over previous
//
#include <hip/hip_runtime.h>
#include <math.h>

#define Bq 4
#define Hq 16
#define Nq 4096
#define Dq 64
#define Mq 128
#define Cq 32                          /* chunks per (b,h); L = 128 */
#define Lq 128
#define EPS_PHI 1e-4f
#define EPS_DEN 1e-6f
#define SCALE 0.35355339059327373f     /* 64^-0.25 */
#define INVSQRT_M 0.08838834764831845f /* 1/sqrt(128) */
#define STATE_STRIDE 8320              /* 128*64 S + 128 z */

#define PSTR 264   /* [A_s | PQ] row stride, bf16 (256+8: 16B-mult, bank-rotating) */
#define KSTR 136   /* PK / PKt / Vt row stride, bf16 (128+8) */
#define WSTR 264   /* Wt row stride, bf16 */

typedef __attribute__((ext_vector_type(8))) short bf16x8;
typedef __attribute__((ext_vector_type(4))) float f32x4;

static __device__ inline f32x4 mfma16(bf16x8 a, bf16x8 b, f32x4 c) {
    return __builtin_amdgcn_mfma_f32_16x16x32_bf16(a, b, c, 0, 0, 0);
}

static __device__ inline unsigned short f2bf(float f) {
    unsigned u = __builtin_bit_cast(unsigned, f);
    u += 0x7FFF + ((u >> 16) & 1);          /* RNE */
    return (unsigned short)(u >> 16);
}

/* A/B fragment (16x16x32): lane&15 = row(A)/col(B), 8 contiguous k at (lane>>4)*8.
   Build from fp32 global row-major (row stride 64), scaled, bf16-rounded. */
static __device__ inline bf16x8 gfrag(const float* p, float scale) {
    float4 a = *(const float4*)p;
    float4 b = *(const float4*)(p + 4);
    union { bf16x8 v; unsigned short s[8]; } u;
    u.s[0] = f2bf(a.x * scale); u.s[1] = f2bf(a.y * scale);
    u.s[2] = f2bf(a.z * scale); u.s[3] = f2bf(a.w * scale);
    u.s[4] = f2bf(b.x * scale); u.s[5] = f2bf(b.y * scale);
    u.s[6] = f2bf(b.z * scale); u.s[7] = f2bf(b.w * scale);
    return u.v;
}

// ---------------------------------------------------------------------------
// kstat: per (bh,chunk): rowK (=0.5||x||^2) + block max of (proj_k - h).
// 512 threads: 8 waves, one 16-row block each (2 waves/SIMD for latency hiding).
// ---------------------------------------------------------------------------
__global__ __launch_bounds__(512) void kstat_kernel(
    const float* __restrict__ kin, const float* __restrict__ omega,
    float* __restrict__ rowK, float* __restrict__ partial) {
    __shared__ float h_lds[128];
    __shared__ float wred[8];
    const int t = threadIdx.x, w = t >> 6, lane = t & 63;
    const int c16 = lane & 15, qd = lane >> 4;
    const int bx = blockIdx.x;
    const size_t rowbase = (size_t)(bx >> 5) * Nq + (size_t)(bx & 31) * Lq;
    const float* kb = kin + rowbase * 64;

    #pragma unroll
    for (int rep = 0; rep < 16; ++rep) {          /* h pass: wave-per-row */
        int e = rep * 512 + t;
        int l = e >> 6;                            /* wave-uniform */
        float x = kb[e] * SCALE;
        float s = x * x;
        #pragma unroll
        for (int o = 1; o <= 32; o <<= 1) s += __shfl_xor(s, o);
        if (lane == 0) { h_lds[l] = 0.5f * s; rowK[rowbase + l] = 0.5f * s; }
    }
    __syncthreads();

    f32x4 acc[8];
    #pragma unroll
    for (int nt = 0; nt < 8; ++nt) acc[nt] = (f32x4){0.f, 0.f, 0.f, 0.f};
    #pragma unroll
    for (int kt = 0; kt < 2; ++kt) {
        bf16x8 a = gfrag(kb + (size_t)(16 * w + c16) * 64 + kt * 32 + qd * 8, SCALE);
        #pragma unroll
        for (int nt = 0; nt < 8; ++nt) {
            bf16x8 b = gfrag(omega + (size_t)(16 * nt + c16) * 64 + kt * 32 + qd * 8, 1.0f);
            acc[nt] = mfma16(a, b, acc[nt]);
        }
    }
    float lmax = -1e30f;
    const int row0 = 16 * w + 4 * qd;
    #pragma unroll
    for (int r = 0; r < 4; ++r) {
        float h = h_lds[row0 + r];
        #pragma unroll
        for (int nt = 0; nt < 8; ++nt) lmax = fmaxf(lmax, acc[nt][r] - h);
    }
    #pragma unroll
    for (int o = 1; o <= 32; o <<= 1) lmax = fmaxf(lmax, __shfl_xor(lmax, o));
    if (lane == 0) wred[w] = lmax;
    __syncthreads();
    if (t == 0) {
        float m = wred[0];
        #pragma unroll
        for (int i = 1; i < 8; ++i) m = fmaxf(m, wred[i]);
        partial[bx] = m;
    }
}

// ---------------------------------------------------------------------------
__global__ void gmax_kernel(const float* __restrict__ partial, int n, float* __restrict__ gmax) {
    float m = -1e30f;
    for (int i = threadIdx.x; i < n; i += 256) m = fmaxf(m, partial[i]);
    #pragma unroll
    for (int o = 1; o <= 32; o <<= 1) m = fmaxf(m, __shfl_xor(m, o));
    __shared__ float w[4];
    if ((threadIdx.x & 63) == 0) w[threadIdx.x >> 6] = m;
    __syncthreads();
    if (threadIdx.x == 0) gmax[0] = fmaxf(fmaxf(w[0], w[1]), fmaxf(w[2], w[3]));
}

// ---------------------------------------------------------------------------
// chunkstate: S_c = PK^T V (MFMA), z_c via appended ones-column.
// 512 threads, VGPR-capped to 128 so 2 blocks/CU (16 waves/CU = 4/SIMD).
// ---------------------------------------------------------------------------
__global__ __launch_bounds__(512, 4) void chunkstate_kernel(
    const float* __restrict__ kin, const float* __restrict__ vin,
    const float* __restrict__ omega, const float* __restrict__ rowK,
    const float* __restrict__ gmaxp, float* __restrict__ Sbuf) {
    __shared__ __align__(16) unsigned short PKt[128 * KSTR]; /* [m][l] */
    __shared__ __align__(16) unsigned short Vt[80 * KSTR];   /* [d|1][l] */
    const int t = threadIdx.x, w = t >> 6, lane = t & 63;
    const int c16 = lane & 15, qd = lane >> 4;
    const int bx = blockIdx.x;
    const size_t rowbase = (size_t)(bx >> 5) * Nq + (size_t)(bx & 31) * Lq;
    const float* kb = kin + rowbase * 64;
    const float* vb = vin + rowbase * 64;
    const float gmax = gmaxp[0];

    f32x4 acc[8];
    #pragma unroll
    for (int nt = 0; nt < 8; ++nt) acc[nt] = (f32x4){0.f, 0.f, 0.f, 0.f};
    #pragma unroll
    for (int kt = 0; kt < 2; ++kt) {
        bf16x8 a = gfrag(kb + (size_t)(16 * w + c16) * 64 + kt * 32 + qd * 8, SCALE);
        #pragma unroll
        for (int nt = 0; nt < 8; ++nt) {
            bf16x8 b = gfrag(omega + (size_t)(16 * nt + c16) * 64 + kt * 32 + qd * 8, 1.0f);
            acc[nt] = mfma16(a, b, acc[nt]);
        }
    }
    const int row0 = 16 * w + 4 * qd;
    #pragma unroll
    for (int r = 0; r < 4; ++r) {
        float h = rowK[rowbase + row0 + r];
        #pragma unroll
        for (int nt = 0; nt < 8; ++nt) {
            float pk = __expf(acc[nt][r] - h - gmax) * INVSQRT_M + EPS_PHI;
            PKt[(16 * nt + c16) * KSTR + row0 + r] = f2bf(pk);
        }
    }
    #pragma unroll
    for (int rep = 0; rep < 16; ++rep) {          /* Vt[d][l] = V[l][d] */
        int e = rep * 512 + t;
        Vt[(e & 63) * KSTR + (e >> 6)] = f2bf(vb[e]);
    }
    if (t < 128) Vt[64 * KSTR + t] = 0x3F80;      /* ones column -> z */
    __syncthreads();

    f32x4 acc2[5];
    #pragma unroll
    for (int nt = 0; nt < 5; ++nt) acc2[nt] = (f32x4){0.f, 0.f, 0.f, 0.f};
    #pragma unroll
    for (int kt = 0; kt < 4; ++kt) {
        bf16x8 a = *(const bf16x8*)&PKt[(16 * w + c16) * KSTR + kt * 32 + qd * 8];
        #pragma unroll
        for (int nt = 0; nt < 5; ++nt) {
            bf16x8 b = *(const bf16x8*)&Vt[(16 * nt + c16) * KSTR + kt * 32 + qd * 8];
            acc2[nt] = mfma16(a, b, acc2[nt]);
        }
    }
    float* sb = Sbuf + (size_t)bx * STATE_STRIDE;
    const int m0 = 16 * w + 4 * qd;
    #pragma unroll
    for (int r = 0; r < 4; ++r) {
        #pragma unroll
        for (int nt = 0; nt < 4; ++nt)
            sb[(m0 + r) * 64 + 16 * nt + c16] = acc2[nt][r];
        if (c16 == 0) sb[8192 + m0 + r] = acc2[4][r];
    }
}

// ---------------------------------------------------------------------------
// prefix: in-place exclusive prefix of chunk states per (b,h).
// One thread per independent chain (8320 per bh); 64*33 blocks so all CUs work.
// ---------------------------------------------------------------------------
#define PBLK 33   /* ceil(8320/256) slices per (b,h) */
__global__ __launch_bounds__(256) void prefix_kernel(float* __restrict__ Sbuf) {
    const int bh = blockIdx.x / PBLK;
    const int e = (blockIdx.x % PBLK) * 256 + threadIdx.x;
    if (e >= STATE_STRIDE) return;
    float running = 0.f;
    size_t idx = (size_t)bh * Cq * STATE_STRIDE + e;
    for (int c = 0; c < Cq; ++c, idx += STATE_STRIDE) {
        float tmp = Sbuf[idx];
        Sbuf[idx] = running;
        running += tmp;
    }
}

// ---------------------------------------------------------------------------
// replay: per (bh,chunk): proj via MFMA, phi, A_s = tril(PQ PK^T),
// [num|den] = [A_s|PQ] . [V,1 ; S_in,z_in]. One barrier total.
// 512 threads: 8 waves (2/SIMD), one 16-row block each; proj_q/proj_k fused
// so omega fragments are loaded once and the two MFMA chains are independent.
// ---------------------------------------------------------------------------
__global__ __launch_bounds__(512, 2) void replay_kernel(
    const float* __restrict__ q, const float* __restrict__ kin,
    const float* __restrict__ vin, const float* __restrict__ omega,
    const float* __restrict__ rowK, const float* __restrict__ gmaxp,
    const float* __restrict__ Sbuf, float* __restrict__ out) {
    __shared__ __align__(16) unsigned short P[128 * PSTR];   /* [A_s | PQ] */
    __shared__ __align__(16) unsigned short PK[128 * KSTR];  /* [l][m] */
    __shared__ __align__(16) unsigned short Wt[80 * WSTR];   /* [d|wz][l;128+m] */
    const int t = threadIdx.x, w = t >> 6, lane = t & 63;
    const int c16 = lane & 15, qd = lane >> 4;
    const int bx = blockIdx.x;
    const size_t rowbase = (size_t)(bx >> 5) * Nq + (size_t)(bx & 31) * Lq;
    const float* qb = q + rowbase * 64;
    const float* kb = kin + rowbase * 64;
    const float* vb = vin + rowbase * 64;
    const float gmax = gmaxp[0];

    /* ---- proj_q + proj_k fused (shared omega fragments, 2 indep MFMA chains) */
    f32x4 accq[8], acck[8];
    #pragma unroll
    for (int nt = 0; nt < 8; ++nt) {
        accq[nt] = (f32x4){0.f, 0.f, 0.f, 0.f};
        acck[nt] = (f32x4){0.f, 0.f, 0.f, 0.f};
    }
    #pragma unroll
    for (int kt = 0; kt < 2; ++kt) {
        bf16x8 aq = gfrag(qb + (size_t)(16 * w + c16) * 64 + kt * 32 + qd * 8, SCALE);
        bf16x8 ak = gfrag(kb + (size_t)(16 * w + c16) * 64 + kt * 32 + qd * 8, SCALE);
        #pragma unroll
        for (int nt = 0; nt < 8; ++nt) {
            bf16x8 b = gfrag(omega + (size_t)(16 * nt + c16) * 64 + kt * 32 + qd * 8, 1.0f);
            accq[nt] = mfma16(aq, b, accq[nt]);
            acck[nt] = mfma16(ak, b, acck[nt]);
        }
    }
    const int row0 = 16 * w + 4 * qd;
    /* ---- phi_q: h cancels against per-row max; write PQ into P[:,128:] ---- */
    #pragma unroll
    for (int r = 0; r < 4; ++r) {
        float mx = accq[0][r];
        #pragma unroll
        for (int nt = 1; nt < 8; ++nt) mx = fmaxf(mx, accq[nt][r]);
        mx = fmaxf(mx, __shfl_xor(mx, 1));
        mx = fmaxf(mx, __shfl_xor(mx, 2));
        mx = fmaxf(mx, __shfl_xor(mx, 4));
        mx = fmaxf(mx, __shfl_xor(mx, 8));
        #pragma unroll
        for (int nt = 0; nt < 8; ++nt) {
            float pq = __expf(accq[nt][r] - mx) * INVSQRT_M + EPS_PHI;
            P[(row0 + r) * PSTR + 128 + 16 * nt + c16] = f2bf(pq);
        }
    }
    /* ---- phi_k -> PK[l][m] ---- */
    #pragma unroll
    for (int r = 0; r < 4; ++r) {
        float h = rowK[rowbase + row0 + r];
        #pragma unroll
        for (int nt = 0; nt < 8; ++nt) {
            float pk = __expf(acck[nt][r] - h - gmax) * INVSQRT_M + EPS_PHI;
            PK[(row0 + r) * KSTR + 16 * nt + c16] = f2bf(pk);
        }
    }
    /* ---- Wt fill: [V;S_in] transposed + w_z column ---- */
    const float* sb = Sbuf + (size_t)bx * STATE_STRIDE;
    #pragma unroll
    for (int rep = 0; rep < 16; ++rep) {
        int e = rep * 512 + t;
        Wt[(e & 63) * WSTR + (e >> 6)] = f2bf(vb[e]);
    }
    #pragma unroll
    for (int rep = 0; rep < 16; ++rep) {
        int e = rep * 512 + t;
        Wt[(e & 63) * WSTR + 128 + (e >> 6)] = f2bf(sb[e]);
    }
    if (t < 128)      Wt[64 * WSTR + t] = 0x3F80;                  /* ones over V rows */
    else if (t < 256) Wt[64 * WSTR + t] = f2bf(sb[8192 + (t - 128)]); /* z_in over S rows */
    __syncthreads();   /* the ONE barrier: PK + Wt cross-wave visibility */

    /* ---- GEMM1: A_s = PQ . PK^T (A rows are wave-private) ---- */
    f32x4 acc[8];
    #pragma unroll
    for (int nt = 0; nt < 8; ++nt) acc[nt] = (f32x4){0.f, 0.f, 0.f, 0.f};
    #pragma unroll
    for (int kt = 0; kt < 4; ++kt) {
        bf16x8 a = *(const bf16x8*)&P[(16 * w + c16) * PSTR + 128 + kt * 32 + qd * 8];
        #pragma unroll
        for (int nt = 0; nt < 8; ++nt) {
            bf16x8 b = *(const bf16x8*)&PK[(16 * nt + c16) * KSTR + kt * 32 + qd * 8];
            acc[nt] = mfma16(a, b, acc[nt]);
        }
    }
    /* ---- causal mask + write A_s into P[:,0:128] (own rows) ---- */
    #pragma unroll
    for (int r = 0; r < 4; ++r) {
        #pragma unroll
        for (int nt = 0; nt < 8; ++nt) {
            int col = 16 * nt + c16;
            float vm = (col <= row0 + r) ? acc[nt][r] : 0.f;
            P[(row0 + r) * PSTR + col] = f2bf(vm);
        }
    }
    /* ---- GEMM2: [num|den] = P . Wt^T (A own rows, B ready since barrier) ---- */
    f32x4 acc2[5];
    #pragma unroll
    for (int nt = 0; nt < 5; ++nt) acc2[nt] = (f32x4){0.f, 0.f, 0.f, 0.f};
    #pragma unroll
    for (int kt = 0; kt < 8; ++kt) {
        bf16x8 a = *(const bf16x8*)&P[(16 * w + c16) * PSTR + kt * 32 + qd * 8];
        #pragma unroll
        for (int nt = 0; nt < 5; ++nt) {
            bf16x8 b = *(const bf16x8*)&Wt[(16 * nt + c16) * WSTR + kt * 32 + qd * 8];
            acc2[nt] = mfma16(a, b, acc2[nt]);
        }
    }
    /* ---- epilogue: den broadcast from col-64 holder lane (c16==0) ---- */
    #pragma unroll
    for (int r = 0; r < 4; ++r) {
        float den = __shfl(acc2[4][r], lane & 48) + EPS_DEN;
        float rd = 1.0f / den;
        #pragma unroll
        for (int nt = 0; nt < 4; ++nt)
            out[(rowbase + row0 + r) * 64 + 16 * nt + c16] = acc2[nt][r] * rd;
    }
}

// ---------------------------------------------------------------------------
extern "C" void kernel_launch(void* const* d_in, const int* in_sizes, int n_in,
                              void* d_out, int out_size, void* d_ws, size_t ws_size,
                              hipStream_t stream) {
    const float* q     = (const float*)d_in[0];
    const float* k     = (const float*)d_in[1];
    const float* v     = (const float*)d_in[2];
    const float* omega = (const float*)d_in[3];
    float* out = (float*)d_out;
    float* ws  = (float*)d_ws;

    const int totalRows = Bq * Hq * Nq;          /* 262144 */
    const int nChunks   = Bq * Hq * Cq;          /* 2048 */
    float* rowK    = ws;                         /* 262144 */
    float* partial = rowK + totalRows;           /* 2048 */
    float* gmax    = partial + nChunks;          /* 1 (+pad) */
    float* Sbuf    = gmax + 16;                  /* 2048 * 8320 = 68.2 MB */

    kstat_kernel<<<nChunks, 512, 0, stream>>>(k, omega, rowK, partial);
    gmax_kernel<<<1, 256, 0, stream>>>(partial, nChunks, gmax);
    chunkstate_kernel<<<nChunks, 512, 0, stream>>>(k, v, omega, rowK, gmax, Sbuf);
    prefix_kernel<<<64 * PBLK, 256, 0, stream>>>(Sbuf);
    replay_kernel<<<nChunks, 512, 0, stream>>>(q, k, v, omega, rowK, gmax, Sbuf, out);
}

// Round 2
// 483.701 us; speedup vs baseline: 1.1476x; 1.0004x over previous
//
#include <hip/hip_runtime.h>
#include <math.h>

#define Bq 4
#define Hq 16
#define Nq 4096
#define Dq 64
#define Mq 128
#define Cq 32                          /* chunks per (b,h); L = 128 */
#define Lq 128
#define EPS_PHI 1e-4f
#define EPS_DEN 1e-6f
#define SCALE 0.35355339059327373f     /* 64^-0.25 */
#define INVSQRT_M 0.08838834764831845f /* 1/sqrt(128) */
#define STATE_STRIDE 8320              /* 128*64 S + 128 z */

#define PSTR 264   /* [A_s | PQ] row stride, bf16 (256+8: 16B-mult, bank-rotating) */
#define KSTR 136   /* PK / PKt / Vt row stride, bf16 (128+8) */
#define WSTR 264   /* Wt row stride, bf16 */

typedef __attribute__((ext_vector_type(8))) short bf16x8;
typedef __attribute__((ext_vector_type(4))) float f32x4;

static __device__ inline f32x4 mfma16(bf16x8 a, bf16x8 b, f32x4 c) {
    return __builtin_amdgcn_mfma_f32_16x16x32_bf16(a, b, c, 0, 0, 0);
}

static __device__ inline unsigned short f2bf(float f) {
    unsigned u = __builtin_bit_cast(unsigned, f);
    u += 0x7FFF + ((u >> 16) & 1);          /* RNE */
    return (unsigned short)(u >> 16);
}

/* A/B fragment (16x16x32): lane&15 = row(A)/col(B), 8 contiguous k at (lane>>4)*8.
   Build from fp32 global row-major (row stride 64), scaled, bf16-rounded. */
static __device__ inline bf16x8 gfrag(const float* p, float scale) {
    float4 a = *(const float4*)p;
    float4 b = *(const float4*)(p + 4);
    union { bf16x8 v; unsigned short s[8]; } u;
    u.s[0] = f2bf(a.x * scale); u.s[1] = f2bf(a.y * scale);
    u.s[2] = f2bf(a.z * scale); u.s[3] = f2bf(a.w * scale);
    u.s[4] = f2bf(b.x * scale); u.s[5] = f2bf(b.y * scale);
    u.s[6] = f2bf(b.z * scale); u.s[7] = f2bf(b.w * scale);
    return u.v;
}

// ---------------------------------------------------------------------------
// chunkstate (kstat fused): per (bh,chunk):
//   h (=0.5||x||^2) -> rowK, proj_k (MFMA), per-chunk max m_c -> partial,
//   S~_c = PK'^T V with phi' = exp(proj-h-m_c)/sqrt(M)  (NO eps, NO gmax),
//   z~ via ones-column, colsumV_c (f32) for the exact eps term.
// prefix applies  S_c = e^{m_c-gmax} S~_c + eps*colsumV  afterwards.
// 512 threads, VGPR-capped so 2 blocks/CU (4 waves/SIMD).
// ---------------------------------------------------------------------------
__global__ __launch_bounds__(512, 4) void chunkstate_kernel(
    const float* __restrict__ kin, const float* __restrict__ vin,
    const float* __restrict__ omega, float* __restrict__ rowK,
    float* __restrict__ partial, float* __restrict__ Sbuf,
    float* __restrict__ csumV) {
    __shared__ __align__(16) unsigned short PKt[128 * KSTR]; /* [m][l] */
    __shared__ __align__(16) unsigned short Vt[80 * KSTR];   /* [d|1][l] */
    __shared__ float h_lds[128];
    __shared__ float wred[8];
    __shared__ float csum[8][64];
    const int t = threadIdx.x, w = t >> 6, lane = t & 63;
    const int c16 = lane & 15, qd = lane >> 4;
    const int bx = blockIdx.x;
    const size_t rowbase = (size_t)(bx >> 5) * Nq + (size_t)(bx & 31) * Lq;
    const float* kb = kin + rowbase * 64;
    const float* vb = vin + rowbase * 64;

    /* ---- h pass: wave-per-row shuffle reduce, coalesced reads ---- */
    #pragma unroll
    for (int rep = 0; rep < 16; ++rep) {
        int e = rep * 512 + t;
        int l = rep * 8 + w;                       /* wave-uniform */
        float x = kb[e] * SCALE;
        float s = x * x;
        #pragma unroll
        for (int o = 1; o <= 32; o <<= 1) s += __shfl_xor(s, o);
        if (lane == 0) { h_lds[l] = 0.5f * s; rowK[rowbase + l] = 0.5f * s; }
    }
    __syncthreads();

    /* ---- proj_k via MFMA ---- */
    f32x4 acc[8];
    #pragma unroll
    for (int nt = 0; nt < 8; ++nt) acc[nt] = (f32x4){0.f, 0.f, 0.f, 0.f};
    #pragma unroll
    for (int kt = 0; kt < 2; ++kt) {
        bf16x8 a = gfrag(kb + (size_t)(16 * w + c16) * 64 + kt * 32 + qd * 8, SCALE);
        #pragma unroll
        for (int nt = 0; nt < 8; ++nt) {
            bf16x8 b = gfrag(omega + (size_t)(16 * nt + c16) * 64 + kt * 32 + qd * 8, 1.0f);
            acc[nt] = mfma16(a, b, acc[nt]);
        }
    }
    const int row0 = 16 * w + 4 * qd;
    /* ---- chunk max ---- */
    float lmax = -1e30f;
    #pragma unroll
    for (int r = 0; r < 4; ++r) {
        float h = h_lds[row0 + r];
        #pragma unroll
        for (int nt = 0; nt < 8; ++nt) lmax = fmaxf(lmax, acc[nt][r] - h);
    }
    #pragma unroll
    for (int o = 1; o <= 32; o <<= 1) lmax = fmaxf(lmax, __shfl_xor(lmax, o));
    if (lane == 0) wred[w] = lmax;
    /* ---- colsumV partials (f32, exact): group g sums 16 l-rows ---- */
    {
        const int d = t & 63, g = t >> 6;
        float s = 0.f;
        #pragma unroll
        for (int j = 0; j < 16; ++j) s += vb[(16 * g + j) * 64 + d];
        csum[g][d] = s;
    }
    __syncthreads();
    float mc = wred[0];
    #pragma unroll
    for (int i = 1; i < 8; ++i) mc = fmaxf(mc, wred[i]);
    if (t == 0) partial[bx] = mc;

    /* ---- phi'_k -> PKt[m][l]  (no eps; bounded by 1/sqrt(M)) ---- */
    #pragma unroll
    for (int r = 0; r < 4; ++r) {
        float h = h_lds[row0 + r];
        #pragma unroll
        for (int nt = 0; nt < 8; ++nt) {
            float pk = __expf(acc[nt][r] - h - mc) * INVSQRT_M;
            PKt[(16 * nt + c16) * KSTR + row0 + r] = f2bf(pk);
        }
    }
    #pragma unroll
    for (int rep = 0; rep < 16; ++rep) {          /* Vt[d][l] = V[l][d] */
        int e = rep * 512 + t;
        Vt[(e & 63) * KSTR + (e >> 6)] = f2bf(vb[e]);
    }
    if (t < 128) Vt[64 * KSTR + t] = 0x3F80;      /* ones column -> z~ */
    __syncthreads();

    f32x4 acc2[5];
    #pragma unroll
    for (int nt = 0; nt < 5; ++nt) acc2[nt] = (f32x4){0.f, 0.f, 0.f, 0.f};
    #pragma unroll
    for (int kt = 0; kt < 4; ++kt) {
        bf16x8 a = *(const bf16x8*)&PKt[(16 * w + c16) * KSTR + kt * 32 + qd * 8];
        #pragma unroll
        for (int nt = 0; nt < 5; ++nt) {
            bf16x8 b = *(const bf16x8*)&Vt[(16 * nt + c16) * KSTR + kt * 32 + qd * 8];
            acc2[nt] = mfma16(a, b, acc2[nt]);
        }
    }
    float* sb = Sbuf + (size_t)bx * STATE_STRIDE;
    #pragma unroll
    for (int r = 0; r < 4; ++r) {
        #pragma unroll
        for (int nt = 0; nt < 4; ++nt)
            sb[(row0 + r) * 64 + 16 * nt + c16] = acc2[nt][r];
        if (c16 == 0) sb[8192 + row0 + r] = acc2[4][r];
    }
    if (t < 64) {                                  /* colsumV finalize */
        float s = 0.f;
        #pragma unroll
        for (int g = 0; g < 8; ++g) s += csum[g][t];
        csumV[(size_t)bx * 64 + t] = s;
    }
}

// ---------------------------------------------------------------------------
__global__ void gmax_kernel(const float* __restrict__ partial, int n, float* __restrict__ gmax) {
    float m = -1e30f;
    for (int i = threadIdx.x; i < n; i += 256) m = fmaxf(m, partial[i]);
    #pragma unroll
    for (int o = 1; o <= 32; o <<= 1) m = fmaxf(m, __shfl_xor(m, o));
    __shared__ float w[4];
    if ((threadIdx.x & 63) == 0) w[threadIdx.x >> 6] = m;
    __syncthreads();
    if (threadIdx.x == 0) gmax[0] = fmaxf(fmaxf(w[0], w[1]), fmaxf(w[2], w[3]));
}

// ---------------------------------------------------------------------------
// prefix: exclusive prefix of  e^{m_c-gmax} S~_c + eps*colsumV (exact eps).
// One thread per chain element; 64*PBLK blocks so all CUs work.
// ---------------------------------------------------------------------------
#define PBLK 33   /* ceil(8320/256) slices per (b,h) */
__global__ __launch_bounds__(256) void prefix_kernel(
    float* __restrict__ Sbuf, const float* __restrict__ csumV,
    const float* __restrict__ partial, const float* __restrict__ gmaxp) {
    const int bh = blockIdx.x / PBLK;
    const int e = (blockIdx.x % PBLK) * 256 + threadIdx.x;
    if (e >= STATE_STRIDE) return;
    const float gm = gmaxp[0];
    const int isZ = (e >= 8192);
    const int d = e & 63;
    float running = 0.f;
    size_t idx = (size_t)bh * Cq * STATE_STRIDE + e;
    #pragma unroll 4
    for (int c = 0; c < Cq; ++c, idx += STATE_STRIDE) {
        const int cx = bh * Cq + c;
        float sc = __expf(partial[cx] - gm);
        float epsterm = isZ ? (EPS_PHI * 128.0f)
                            : (EPS_PHI * csumV[(size_t)cx * 64 + d]);
        float tmp = sc * Sbuf[idx] + epsterm;
        Sbuf[idx] = running;
        running += tmp;
    }
}

// ---------------------------------------------------------------------------
// replay: per (bh,chunk): proj via MFMA, phi, A_s = tril(PQ PK^T),
// [num|den] = [A_s|PQ] . [V,1 ; S_in,z_in].
// 1024 threads = 16 waves (4/SIMD): wave pair (p, role) per 16-row block.
//   role 0: proj_q/phi_q; role 1: proj_k/phi_k.
//   GEMM1 split over output cols (nt 0-3 vs 4-7), GEMM2 over tiles
//   ({0,1,den} vs {2,3,den}; den duplicated so no extra barrier).
// ---------------------------------------------------------------------------
__global__ __launch_bounds__(1024, 4) void replay_kernel(
    const float* __restrict__ q, const float* __restrict__ kin,
    const float* __restrict__ vin, const float* __restrict__ omega,
    const float* __restrict__ rowK, const float* __restrict__ gmaxp,
    const float* __restrict__ Sbuf, float* __restrict__ out) {
    __shared__ __align__(16) unsigned short P[128 * PSTR];   /* [A_s | PQ] */
    __shared__ __align__(16) unsigned short PK[128 * KSTR];  /* [l][m] */
    __shared__ __align__(16) unsigned short Wt[80 * WSTR];   /* [d|wz][l;128+m] */
    const int t = threadIdx.x, w = t >> 6, lane = t & 63;
    const int c16 = lane & 15, qd = lane >> 4;
    const int p = w & 7, rho = w >> 3;
    const int bx = blockIdx.x;
    const size_t rowbase = (size_t)(bx >> 5) * Nq + (size_t)(bx & 31) * Lq;
    const float* qb = q + rowbase * 64;
    const float* kb = kin + rowbase * 64;
    const float* vb = vin + rowbase * 64;
    const float gmax = gmaxp[0];
    const int row0 = 16 * p + 4 * qd;
    const int arow = 16 * p + c16;

    /* ---- proj: role 0 -> q rows, role 1 -> k rows ---- */
    const float* xb = rho ? kb : qb;
    f32x4 acc[8];
    #pragma unroll
    for (int nt = 0; nt < 8; ++nt) acc[nt] = (f32x4){0.f, 0.f, 0.f, 0.f};
    #pragma unroll
    for (int kt = 0; kt < 2; ++kt) {
        bf16x8 a = gfrag(xb + (size_t)arow * 64 + kt * 32 + qd * 8, SCALE);
        #pragma unroll
        for (int nt = 0; nt < 8; ++nt) {
            bf16x8 b = gfrag(omega + (size_t)(16 * nt + c16) * 64 + kt * 32 + qd * 8, 1.0f);
            acc[nt] = mfma16(a, b, acc[nt]);
        }
    }
    if (rho == 0) {
        /* phi_q: h cancels against per-row max; write PQ into P[:,128:] */
        #pragma unroll
        for (int r = 0; r < 4; ++r) {
            float mx = acc[0][r];
            #pragma unroll
            for (int nt = 1; nt < 8; ++nt) mx = fmaxf(mx, acc[nt][r]);
            mx = fmaxf(mx, __shfl_xor(mx, 1));
            mx = fmaxf(mx, __shfl_xor(mx, 2));
            mx = fmaxf(mx, __shfl_xor(mx, 4));
            mx = fmaxf(mx, __shfl_xor(mx, 8));
            #pragma unroll
            for (int nt = 0; nt < 8; ++nt) {
                float pq = __expf(acc[nt][r] - mx) * INVSQRT_M + EPS_PHI;
                P[(row0 + r) * PSTR + 128 + 16 * nt + c16] = f2bf(pq);
            }
        }
    } else {
        /* phi_k -> PK[l][m] */
        #pragma unroll
        for (int r = 0; r < 4; ++r) {
            float h = rowK[rowbase + row0 + r];
            #pragma unroll
            for (int nt = 0; nt < 8; ++nt) {
                float pk = __expf(acc[nt][r] - h - gmax) * INVSQRT_M + EPS_PHI;
                PK[(row0 + r) * KSTR + 16 * nt + c16] = f2bf(pk);
            }
        }
    }
    /* ---- Wt fill: [V;S_in] transposed + w_z column (1024 threads) ---- */
    const float* sb = Sbuf + (size_t)bx * STATE_STRIDE;
    #pragma unroll
    for (int rep = 0; rep < 8; ++rep) {
        int e = rep * 1024 + t;
        Wt[(e & 63) * WSTR + (e >> 6)] = f2bf(vb[e]);
    }
    #pragma unroll
    for (int rep = 0; rep < 8; ++rep) {
        int e = rep * 1024 + t;
        Wt[(e & 63) * WSTR + 128 + (e >> 6)] = f2bf(sb[e]);
    }
    if (t < 128)      Wt[64 * WSTR + t] = 0x3F80;                     /* ones over V rows */
    else if (t < 256) Wt[64 * WSTR + t] = f2bf(sb[8192 + (t - 128)]); /* z_in over S rows */
    __syncthreads();   /* barrier 1: PQ + PK + Wt cross-wave visibility */

    /* ---- GEMM1: A_s[,64*rho:64*rho+64) = PQ . PK^T ---- */
    f32x4 acc1[4];
    #pragma unroll
    for (int j = 0; j < 4; ++j) acc1[j] = (f32x4){0.f, 0.f, 0.f, 0.f};
    #pragma unroll
    for (int kt = 0; kt < 4; ++kt) {
        bf16x8 a = *(const bf16x8*)&P[arow * PSTR + 128 + kt * 32 + qd * 8];
        #pragma unroll
        for (int j = 0; j < 4; ++j) {
            const int nt = 4 * rho + j;
            bf16x8 b = *(const bf16x8*)&PK[(16 * nt + c16) * KSTR + kt * 32 + qd * 8];
            acc1[j] = mfma16(a, b, acc1[j]);
        }
    }
    /* ---- causal mask + write A_s half into P[:,0:128] ---- */
    #pragma unroll
    for (int r = 0; r < 4; ++r) {
        #pragma unroll
        for (int j = 0; j < 4; ++j) {
            const int col = 16 * (4 * rho + j) + c16;
            float vm = (col <= row0 + r) ? acc1[j][r] : 0.f;
            P[(row0 + r) * PSTR + col] = f2bf(vm);
        }
    }
    __syncthreads();   /* barrier 2: A_s pair-halves visible */

    /* ---- GEMM2: [num|den] = P . Wt^T; role tiles {2rho,2rho+1,den} ---- */
    const int n0 = 2 * rho, n1 = 2 * rho + 1;
    f32x4 acc2[3];
    #pragma unroll
    for (int j = 0; j < 3; ++j) acc2[j] = (f32x4){0.f, 0.f, 0.f, 0.f};
    #pragma unroll
    for (int kt = 0; kt < 8; ++kt) {
        bf16x8 a = *(const bf16x8*)&P[arow * PSTR + kt * 32 + qd * 8];
        bf16x8 b0 = *(const bf16x8*)&Wt[(16 * n0 + c16) * WSTR + kt * 32 + qd * 8];
        bf16x8 b1 = *(const bf16x8*)&Wt[(16 * n1 + c16) * WSTR + kt * 32 + qd * 8];
        bf16x8 b2 = *(const bf16x8*)&Wt[(16 * 4 + c16) * WSTR + kt * 32 + qd * 8];
        acc2[0] = mfma16(a, b0, acc2[0]);
        acc2[1] = mfma16(a, b1, acc2[1]);
        acc2[2] = mfma16(a, b2, acc2[2]);
    }
    /* ---- epilogue: den broadcast from col-64 holder lane (c16==0) ---- */
    #pragma unroll
    for (int r = 0; r < 4; ++r) {
        float den = __shfl(acc2[2][r], lane & 48) + EPS_DEN;
        float rd = 1.0f / den;
        out[(rowbase + row0 + r) * 64 + 16 * n0 + c16] = acc2[0][r] * rd;
        out[(rowbase + row0 + r) * 64 + 16 * n1 + c16] = acc2[1][r] * rd;
    }
}

// ---------------------------------------------------------------------------
extern "C" void kernel_launch(void* const* d_in, const int* in_sizes, int n_in,
                              void* d_out, int out_size, void* d_ws, size_t ws_size,
                              hipStream_t stream) {
    const float* q     = (const float*)d_in[0];
    const float* k     = (const float*)d_in[1];
    const float* v     = (const float*)d_in[2];
    const float* omega = (const float*)d_in[3];
    float* out = (float*)d_out;
    float* ws  = (float*)d_ws;

    const int totalRows = Bq * Hq * Nq;          /* 262144 */
    const int nChunks   = Bq * Hq * Cq;          /* 2048 */
    float* rowK    = ws;                         /* 262144 */
    float* partial = rowK + totalRows;           /* 2048 */
    float* gmax    = partial + nChunks;          /* 1 (+pad) */
    float* Sbuf    = gmax + 16;                  /* 2048 * 8320 = 68.2 MB */
    float* csumV   = Sbuf + (size_t)nChunks * STATE_STRIDE; /* 2048*64 */

    chunkstate_kernel<<<nChunks, 512, 0, stream>>>(k, v, omega, rowK, partial, Sbuf, csumV);
    gmax_kernel<<<1, 256, 0, stream>>>(partial, nChunks, gmax);
    prefix_kernel<<<64 * PBLK, 256, 0, stream>>>(Sbuf, csumV, partial, gmax);
    replay_kernel<<<nChunks, 1024, 0, stream>>>(q, k, v, omega, rowK, gmax, Sbuf, out);
}

// Round 3
// 436.834 us; speedup vs baseline: 1.2707x; 1.1073x over previous
//
#include <hip/hip_runtime.h>
#include <math.h>

#define Bq 4
#define Hq 16
#define Nq 4096
#define Dq 64
#define Mq 128
#define Cq 32                          /* chunks per (b,h); L = 128 */
#define Lq 128
#define EPS_PHI 1e-4f
#define EPS_DEN 1e-6f
#define SCALE 0.35355339059327373f     /* 64^-0.25 */
#define INVSQRT_M 0.08838834764831845f /* 1/sqrt(128) */
#define STATE_STRIDE 8320              /* 128*64 S + 128 z */

#define PSTR 264   /* [A_s | PQ] row stride, bf16 */
#define KSTR 136   /* PK / PKt / Vt row stride, bf16 (128+8) */
#define WSTR 264   /* Wt row stride, bf16 */

/* column permutation on the m axis: lane packing for phi writes.
   perm(m) = (m&15)*8 + (m>>4). Applied consistently to PQ cols, PK cols,
   and Wt's S_in/z rows-of-k, so every contraction over m is just reordered. */
#define PERM(m) (((m) & 15) * 8 + ((m) >> 4))

typedef __attribute__((ext_vector_type(8))) short bf16x8;
typedef __attribute__((ext_vector_type(4))) short s16x4;
typedef __attribute__((ext_vector_type(4))) float f32x4;

static __device__ inline f32x4 mfma16(bf16x8 a, bf16x8 b, f32x4 c) {
    return __builtin_amdgcn_mfma_f32_16x16x32_bf16(a, b, c, 0, 0, 0);
}

static __device__ inline unsigned short f2bf(float f) {
    unsigned u = __builtin_bit_cast(unsigned, f);
    u += 0x7FFF + ((u >> 16) & 1);          /* RNE */
    return (unsigned short)(u >> 16);
}

/* A/B fragment (16x16x32): lane&15 = row(A)/col(B), 8 contiguous k at (lane>>4)*8. */
static __device__ inline bf16x8 gfrag(const float* p, float scale) {
    float4 a = *(const float4*)p;
    float4 b = *(const float4*)(p + 4);
    union { bf16x8 v; unsigned short s[8]; } u;
    u.s[0] = f2bf(a.x * scale); u.s[1] = f2bf(a.y * scale);
    u.s[2] = f2bf(a.z * scale); u.s[3] = f2bf(a.w * scale);
    u.s[4] = f2bf(b.x * scale); u.s[5] = f2bf(b.y * scale);
    u.s[6] = f2bf(b.z * scale); u.s[7] = f2bf(b.w * scale);
    return u.v;
}

// ---------------------------------------------------------------------------
// chunkstate (kstat fused): h -> rowK, proj_k (MFMA), per-chunk max m_c,
// S~_c = PK'^T V, z~ via ones-column, colsumV (f32 exact eps term).
// LDS writes packed: PKt b64 (4 contiguous l), Vt paired b32.
// ---------------------------------------------------------------------------
__global__ __launch_bounds__(512, 4) void chunkstate_kernel(
    const float* __restrict__ kin, const float* __restrict__ vin,
    const float* __restrict__ omega, float* __restrict__ rowK,
    float* __restrict__ partial, float* __restrict__ Sbuf,
    float* __restrict__ csumV) {
    __shared__ __align__(16) unsigned short PKt[128 * KSTR]; /* [m][l] l-contig */
    __shared__ __align__(16) unsigned short Vt[80 * KSTR];   /* [d|1][l] */
    __shared__ float h_lds[128];
    __shared__ float wred[8];
    __shared__ float csum[8][64];
    const int t = threadIdx.x, w = t >> 6, lane = t & 63;
    const int c16 = lane & 15, qd = lane >> 4;
    const int bx = blockIdx.x;
    const size_t rowbase = (size_t)(bx >> 5) * Nq + (size_t)(bx & 31) * Lq;
    const float* kb = kin + rowbase * 64;
    const float* vb = vin + rowbase * 64;

    /* ---- h pass ---- */
    #pragma unroll
    for (int rep = 0; rep < 16; ++rep) {
        int e = rep * 512 + t;
        int l = rep * 8 + w;
        float x = kb[e] * SCALE;
        float s = x * x;
        #pragma unroll
        for (int o = 1; o <= 32; o <<= 1) s += __shfl_xor(s, o);
        if (lane == 0) { h_lds[l] = 0.5f * s; rowK[rowbase + l] = 0.5f * s; }
    }
    __syncthreads();

    /* ---- proj_k via MFMA ---- */
    f32x4 acc[8];
    #pragma unroll
    for (int nt = 0; nt < 8; ++nt) acc[nt] = (f32x4){0.f, 0.f, 0.f, 0.f};
    #pragma unroll
    for (int kt = 0; kt < 2; ++kt) {
        bf16x8 a = gfrag(kb + (size_t)(16 * w + c16) * 64 + kt * 32 + qd * 8, SCALE);
        #pragma unroll
        for (int nt = 0; nt < 8; ++nt) {
            bf16x8 b = gfrag(omega + (size_t)(16 * nt + c16) * 64 + kt * 32 + qd * 8, 1.0f);
            acc[nt] = mfma16(a, b, acc[nt]);
        }
    }
    const int row0 = 16 * w + 4 * qd;
    /* ---- chunk max ---- */
    float lmax = -1e30f;
    #pragma unroll
    for (int r = 0; r < 4; ++r) {
        float h = h_lds[row0 + r];
        #pragma unroll
        for (int nt = 0; nt < 8; ++nt) lmax = fmaxf(lmax, acc[nt][r] - h);
    }
    #pragma unroll
    for (int o = 1; o <= 32; o <<= 1) lmax = fmaxf(lmax, __shfl_xor(lmax, o));
    if (lane == 0) wred[w] = lmax;
    /* ---- colsumV partials (f32 exact) ---- */
    {
        const int d = t & 63, g = t >> 6;
        float s = 0.f;
        #pragma unroll
        for (int j = 0; j < 16; ++j) s += vb[(16 * g + j) * 64 + d];
        csum[g][d] = s;
    }
    __syncthreads();
    float mc = wred[0];
    #pragma unroll
    for (int i = 1; i < 8; ++i) mc = fmaxf(mc, wred[i]);
    if (t == 0) partial[bx] = mc;

    /* ---- phi'_k -> PKt[m][l], packed b64 (4 contiguous l per lane) ---- */
    #pragma unroll
    for (int nt = 0; nt < 8; ++nt) {
        union { s16x4 v; unsigned short s[4]; } u;
        #pragma unroll
        for (int r = 0; r < 4; ++r) {
            float pk = __expf(acc[nt][r] - h_lds[row0 + r] - mc) * INVSQRT_M;
            u.s[r] = f2bf(pk);
        }
        *(s16x4*)&PKt[(16 * nt + c16) * KSTR + row0] = u.v;
    }
    /* ---- Vt[d][l] paired b32 ---- */
    #pragma unroll
    for (int rep = 0; rep < 8; ++rep) {
        int e2 = rep * 512 + t;
        int d = e2 & 63, l2 = e2 >> 6;
        unsigned a = f2bf(vb[(2 * l2) * 64 + d]);
        unsigned b = f2bf(vb[(2 * l2 + 1) * 64 + d]);
        *(unsigned*)&Vt[d * KSTR + 2 * l2] = a | (b << 16);
    }
    if (t < 128) Vt[64 * KSTR + t] = 0x3F80;      /* ones column -> z~ */
    __syncthreads();

    f32x4 acc2[5];
    #pragma unroll
    for (int nt = 0; nt < 5; ++nt) acc2[nt] = (f32x4){0.f, 0.f, 0.f, 0.f};
    #pragma unroll
    for (int kt = 0; kt < 4; ++kt) {
        bf16x8 a = *(const bf16x8*)&PKt[(16 * w + c16) * KSTR + kt * 32 + qd * 8];
        #pragma unroll
        for (int nt = 0; nt < 5; ++nt) {
            bf16x8 b = *(const bf16x8*)&Vt[(16 * nt + c16) * KSTR + kt * 32 + qd * 8];
            acc2[nt] = mfma16(a, b, acc2[nt]);
        }
    }
    float* sb = Sbuf + (size_t)bx * STATE_STRIDE;
    #pragma unroll
    for (int r = 0; r < 4; ++r) {
        #pragma unroll
        for (int nt = 0; nt < 4; ++nt)
            sb[(row0 + r) * 64 + 16 * nt + c16] = acc2[nt][r];
        if (c16 == 0) sb[8192 + row0 + r] = acc2[4][r];
    }
    if (t < 64) {
        float s = 0.f;
        #pragma unroll
        for (int g = 0; g < 8; ++g) s += csum[g][t];
        csumV[(size_t)bx * 64 + t] = s;
    }
}

// ---------------------------------------------------------------------------
__global__ void gmax_kernel(const float* __restrict__ partial, int n, float* __restrict__ gmax) {
    float m = -1e30f;
    for (int i = threadIdx.x; i < n; i += 256) m = fmaxf(m, partial[i]);
    #pragma unroll
    for (int o = 1; o <= 32; o <<= 1) m = fmaxf(m, __shfl_xor(m, o));
    __shared__ float w[4];
    if ((threadIdx.x & 63) == 0) w[threadIdx.x >> 6] = m;
    __syncthreads();
    if (threadIdx.x == 0) gmax[0] = fmaxf(fmaxf(w[0], w[1]), fmaxf(w[2], w[3]));
}

// ---------------------------------------------------------------------------
// prefix: exclusive prefix of  e^{m_c-gmax} S~_c + eps*colsumV.
// ---------------------------------------------------------------------------
#define PBLK 33   /* ceil(8320/256) slices per (b,h) */
__global__ __launch_bounds__(256) void prefix_kernel(
    float* __restrict__ Sbuf, const float* __restrict__ csumV,
    const float* __restrict__ partial, const float* __restrict__ gmaxp) {
    const int bh = blockIdx.x / PBLK;
    const int e = (blockIdx.x % PBLK) * 256 + threadIdx.x;
    if (e >= STATE_STRIDE) return;
    const float gm = gmaxp[0];
    const int isZ = (e >= 8192);
    const int d = e & 63;
    float running = 0.f;
    size_t idx = (size_t)bh * Cq * STATE_STRIDE + e;
    #pragma unroll 4
    for (int c = 0; c < Cq; ++c, idx += STATE_STRIDE) {
        const int cx = bh * Cq + c;
        float sc = __expf(partial[cx] - gm);
        float epsterm = isZ ? (EPS_PHI * 128.0f)
                            : (EPS_PHI * csumV[(size_t)cx * 64 + d]);
        float tmp = sc * Sbuf[idx] + epsterm;
        Sbuf[idx] = running;
        running += tmp;
    }
}

// ---------------------------------------------------------------------------
// replay (R1 512-thread structure, LDS writes packed):
//   phi_q/phi_k -> b128 perm-packed rows; GEMM1 swapped (A_s^T = PK.PQ^T)
//   so causal-masked A_s packs to b64 (own rows -> no extra barrier);
//   GEMM2 k-space = [l natural | perm(m)] on both A (P) and B (Wt).
// ---------------------------------------------------------------------------
__global__ __launch_bounds__(512, 2) void replay_kernel(
    const float* __restrict__ q, const float* __restrict__ kin,
    const float* __restrict__ vin, const float* __restrict__ omega,
    const float* __restrict__ rowK, const float* __restrict__ gmaxp,
    const float* __restrict__ Sbuf, float* __restrict__ out) {
    __shared__ __align__(16) unsigned short P[128 * PSTR];   /* [A_s | PQ(perm)] */
    __shared__ __align__(16) unsigned short PK[128 * KSTR];  /* [l][perm(m)] */
    __shared__ __align__(16) unsigned short Wt[65 * WSTR];   /* [d|wz][l ; 128+perm(m)] */
    const int t = threadIdx.x, w = t >> 6, lane = t & 63;
    const int c16 = lane & 15, qd = lane >> 4;
    const int bx = blockIdx.x;
    const size_t rowbase = (size_t)(bx >> 5) * Nq + (size_t)(bx & 31) * Lq;
    const float* qb = q + rowbase * 64;
    const float* kb = kin + rowbase * 64;
    const float* vb = vin + rowbase * 64;
    const float gmax = gmaxp[0];
    const int row0 = 16 * w + 4 * qd;
    const int arow = 16 * w + c16;

    /* ---- proj_q + proj_k fused (shared omega fragments) ---- */
    f32x4 accq[8], acck[8];
    #pragma unroll
    for (int nt = 0; nt < 8; ++nt) {
        accq[nt] = (f32x4){0.f, 0.f, 0.f, 0.f};
        acck[nt] = (f32x4){0.f, 0.f, 0.f, 0.f};
    }
    #pragma unroll
    for (int kt = 0; kt < 2; ++kt) {
        bf16x8 aq = gfrag(qb + (size_t)arow * 64 + kt * 32 + qd * 8, SCALE);
        bf16x8 ak = gfrag(kb + (size_t)arow * 64 + kt * 32 + qd * 8, SCALE);
        #pragma unroll
        for (int nt = 0; nt < 8; ++nt) {
            bf16x8 b = gfrag(omega + (size_t)(16 * nt + c16) * 64 + kt * 32 + qd * 8, 1.0f);
            accq[nt] = mfma16(aq, b, accq[nt]);
            acck[nt] = mfma16(ak, b, acck[nt]);
        }
    }
    /* ---- phi_q: per-row max; b128 perm-packed write into P[:,128:] ---- */
    #pragma unroll
    for (int r = 0; r < 4; ++r) {
        float mx = accq[0][r];
        #pragma unroll
        for (int nt = 1; nt < 8; ++nt) mx = fmaxf(mx, accq[nt][r]);
        mx = fmaxf(mx, __shfl_xor(mx, 1));
        mx = fmaxf(mx, __shfl_xor(mx, 2));
        mx = fmaxf(mx, __shfl_xor(mx, 4));
        mx = fmaxf(mx, __shfl_xor(mx, 8));
        union { bf16x8 v; unsigned short s[8]; } u;
        #pragma unroll
        for (int nt = 0; nt < 8; ++nt)
            u.s[nt] = f2bf(__expf(accq[nt][r] - mx) * INVSQRT_M + EPS_PHI);
        *(bf16x8*)&P[(row0 + r) * PSTR + 128 + c16 * 8] = u.v;   /* perm cols */
    }
    /* ---- phi_k -> PK[l][perm(m)], b128 packed ---- */
    #pragma unroll
    for (int r = 0; r < 4; ++r) {
        float h = rowK[rowbase + row0 + r];
        union { bf16x8 v; unsigned short s[8]; } u;
        #pragma unroll
        for (int nt = 0; nt < 8; ++nt)
            u.s[nt] = f2bf(__expf(acck[nt][r] - h - gmax) * INVSQRT_M + EPS_PHI);
        *(bf16x8*)&PK[(row0 + r) * KSTR + c16 * 8] = u.v;
    }
    /* ---- Wt fill: V^T paired b32; S_in scalar at perm'd cols; z row ---- */
    const float* sb = Sbuf + (size_t)bx * STATE_STRIDE;
    #pragma unroll
    for (int rep = 0; rep < 8; ++rep) {
        int e2 = rep * 512 + t;
        int d = e2 & 63, l2 = e2 >> 6;
        unsigned a = f2bf(vb[(2 * l2) * 64 + d]);
        unsigned b = f2bf(vb[(2 * l2 + 1) * 64 + d]);
        *(unsigned*)&Wt[d * WSTR + 2 * l2] = a | (b << 16);
    }
    #pragma unroll
    for (int rep = 0; rep < 16; ++rep) {
        int e = rep * 512 + t;
        int m = e >> 6, d = e & 63;
        Wt[d * WSTR + 128 + PERM(m)] = f2bf(sb[e]);
    }
    if (t < 128)      Wt[64 * WSTR + t] = 0x3F80;                      /* ones over l */
    else if (t < 256) Wt[64 * WSTR + 128 + PERM(t - 128)] = f2bf(sb[8192 + (t - 128)]);
    __syncthreads();   /* the ONE barrier */

    /* ---- GEMM1 swapped: D[l][q] = PK . PQ^T (contraction over perm-m) ---- */
    bf16x8 bq[4];
    #pragma unroll
    for (int kt = 0; kt < 4; ++kt)
        bq[kt] = *(const bf16x8*)&P[arow * PSTR + 128 + kt * 32 + qd * 8];
    #pragma unroll
    for (int lt = 0; lt < 8; ++lt) {
        f32x4 a1 = (f32x4){0.f, 0.f, 0.f, 0.f};
        #pragma unroll
        for (int kt = 0; kt < 4; ++kt) {
            bf16x8 a = *(const bf16x8*)&PK[(16 * lt + c16) * KSTR + kt * 32 + qd * 8];
            a1 = mfma16(a, bq[kt], a1);
        }
        /* causal mask (keep l <= q) + b64 packed store to P[q][l] */
        union { s16x4 v; unsigned short s[4]; } u;
        #pragma unroll
        for (int r = 0; r < 4; ++r) {
            int l = 16 * lt + 4 * qd + r;
            u.s[r] = f2bf((l <= arow) ? a1[r] : 0.f);
        }
        *(s16x4*)&P[arow * PSTR + 16 * lt + 4 * qd] = u.v;
    }
    /* ---- GEMM2: [num|den] = P . Wt^T (own rows; same-wave LDS RAW) ---- */
    f32x4 acc2[5];
    #pragma unroll
    for (int nt = 0; nt < 5; ++nt) acc2[nt] = (f32x4){0.f, 0.f, 0.f, 0.f};
    #pragma unroll
    for (int kt = 0; kt < 8; ++kt) {
        bf16x8 a = *(const bf16x8*)&P[arow * PSTR + kt * 32 + qd * 8];
        #pragma unroll
        for (int nt = 0; nt < 5; ++nt) {
            bf16x8 b = *(const bf16x8*)&Wt[(16 * nt + c16) * WSTR + kt * 32 + qd * 8];
            acc2[nt] = mfma16(a, b, acc2[nt]);
        }
    }
    /* ---- epilogue ---- */
    #pragma unroll
    for (int r = 0; r < 4; ++r) {
        float den = __shfl(acc2[4][r], lane & 48) + EPS_DEN;
        float rd = 1.0f / den;
        #pragma unroll
        for (int nt = 0; nt < 4; ++nt)
            out[(rowbase + row0 + r) * 64 + 16 * nt + c16] = acc2[nt][r] * rd;
    }
}

// ---------------------------------------------------------------------------
extern "C" void kernel_launch(void* const* d_in, const int* in_sizes, int n_in,
                              void* d_out, int out_size, void* d_ws, size_t ws_size,
                              hipStream_t stream) {
    const float* q     = (const float*)d_in[0];
    const float* k     = (const float*)d_in[1];
    const float* v     = (const float*)d_in[2];
    const float* omega = (const float*)d_in[3];
    float* out = (float*)d_out;
    float* ws  = (float*)d_ws;

    const int totalRows = Bq * Hq * Nq;          /* 262144 */
    const int nChunks   = Bq * Hq * Cq;          /* 2048 */
    float* rowK    = ws;                         /* 262144 */
    float* partial = rowK + totalRows;           /* 2048 */
    float* gmax    = partial + nChunks;          /* 1 (+pad) */
    float* Sbuf    = gmax + 16;                  /* 2048 * 8320 = 68.2 MB */
    float* csumV   = Sbuf + (size_t)nChunks * STATE_STRIDE; /* 2048*64 */

    chunkstate_kernel<<<nChunks, 512, 0, stream>>>(k, v, omega, rowK, partial, Sbuf, csumV);
    gmax_kernel<<<1, 256, 0, stream>>>(partial, nChunks, gmax);
    prefix_kernel<<<64 * PBLK, 256, 0, stream>>>(Sbuf, csumV, partial, gmax);
    replay_kernel<<<nChunks, 512, 0, stream>>>(q, k, v, omega, rowK, gmax, Sbuf, out);
}

// Round 4
// 360.751 us; speedup vs baseline: 1.5387x; 1.2109x over previous
//
#include <hip/hip_runtime.h>
#include <math.h>

#define Bq 4
#define Hq 16
#define Nq 4096
#define Dq 64
#define Mq 128
#define Cq 32                          /* chunks per (b,h); L = 128 */
#define Lq 128
#define EPS_PHI 1e-4f
#define EPS_DEN 1e-6f
#define SCALE 0.35355339059327373f     /* 64^-0.25 */
#define INVSQRT_M 0.08838834764831845f /* 1/sqrt(128) */
#define STATE_STRIDE 8320              /* 128*64 S + 128 z */

#define KSTR 136   /* PK / PKt / Vt row stride, bf16 (128+8) */
#define WSTR 264   /* Wt row stride, bf16 */

/* column permutation on the m axis: perm(m) = (m&15)*8 + (m>>4).
   Applied consistently to PQ, PK, and Wt's S_in/z k-rows. */
#define PERM(m) (((m) & 15) * 8 + ((m) >> 4))

typedef __attribute__((ext_vector_type(8))) short bf16x8;
typedef __attribute__((ext_vector_type(4))) short s16x4;
typedef __attribute__((ext_vector_type(4))) float f32x4;

static __device__ inline f32x4 mfma16(bf16x8 a, bf16x8 b, f32x4 c) {
    return __builtin_amdgcn_mfma_f32_16x16x32_bf16(a, b, c, 0, 0, 0);
}

static __device__ inline unsigned short f2bf(float f) {
    unsigned u = __builtin_bit_cast(unsigned, f);
    u += 0x7FFF + ((u >> 16) & 1);          /* RNE */
    return (unsigned short)(u >> 16);
}

static __device__ inline bf16x8 gfrag(const float* p, float scale) {
    float4 a = *(const float4*)p;
    float4 b = *(const float4*)(p + 4);
    union { bf16x8 v; unsigned short s[8]; } u;
    u.s[0] = f2bf(a.x * scale); u.s[1] = f2bf(a.y * scale);
    u.s[2] = f2bf(a.z * scale); u.s[3] = f2bf(a.w * scale);
    u.s[4] = f2bf(b.x * scale); u.s[5] = f2bf(b.y * scale);
    u.s[6] = f2bf(b.z * scale); u.s[7] = f2bf(b.w * scale);
    return u.v;
}

/* K fragment loader that also accumulates sum of squares of scaled values
   (h = 0.5*||x*SCALE||^2 computed from the SAME loads as proj). */
static __device__ inline bf16x8 gfrag_h(const float* p, float* hs) {
    float4 a = *(const float4*)p;
    float4 b = *(const float4*)(p + 4);
    float x0 = a.x * SCALE, x1 = a.y * SCALE, x2 = a.z * SCALE, x3 = a.w * SCALE;
    float x4 = b.x * SCALE, x5 = b.y * SCALE, x6 = b.z * SCALE, x7 = b.w * SCALE;
    *hs += x0 * x0 + x1 * x1 + x2 * x2 + x3 * x3
         + x4 * x4 + x5 * x5 + x6 * x6 + x7 * x7;
    union { bf16x8 v; unsigned short s[8]; } u;
    u.s[0] = f2bf(x0); u.s[1] = f2bf(x1); u.s[2] = f2bf(x2); u.s[3] = f2bf(x3);
    u.s[4] = f2bf(x4); u.s[5] = f2bf(x5); u.s[6] = f2bf(x6); u.s[7] = f2bf(x7);
    return u.v;
}

// ---------------------------------------------------------------------------
// chunkstate: proj_k (h folded into loads), per-chunk max m_c -> partial,
// S~_c = PK'^T V with phi' = exp(proj-h-m_c)/sqrt(M), z~ via ones-column,
// colsumV (f32 eps term). prefix applies e^{m_c-gmax} + eps afterwards.
// ---------------------------------------------------------------------------
__global__ __launch_bounds__(512, 4) void chunkstate_kernel(
    const float* __restrict__ kin, const float* __restrict__ vin,
    const float* __restrict__ omega,
    float* __restrict__ partial, float* __restrict__ Sbuf,
    float* __restrict__ csumV) {
    __shared__ __align__(16) unsigned short PKt[128 * KSTR]; /* [m][l] */
    __shared__ __align__(16) unsigned short Vt[80 * KSTR];   /* [d|1][l] */
    __shared__ float wred[8];
    __shared__ float csum[8][64];
    const int t = threadIdx.x, w = t >> 6, lane = t & 63;
    const int c16 = lane & 15, qd = lane >> 4;
    const int bx = blockIdx.x;
    const size_t rowbase = (size_t)(bx >> 5) * Nq + (size_t)(bx & 31) * Lq;
    const float* kb = kin + rowbase * 64;
    const float* vb = vin + rowbase * 64;

    /* ---- proj_k via MFMA, h accumulated from the same loads ---- */
    f32x4 acc[8];
    float ssum = 0.f;
    #pragma unroll
    for (int nt = 0; nt < 8; ++nt) acc[nt] = (f32x4){0.f, 0.f, 0.f, 0.f};
    #pragma unroll
    for (int kt = 0; kt < 2; ++kt) {
        bf16x8 a = gfrag_h(kb + (size_t)(16 * w + c16) * 64 + kt * 32 + qd * 8, &ssum);
        #pragma unroll
        for (int nt = 0; nt < 8; ++nt) {
            bf16x8 b = gfrag(omega + (size_t)(16 * nt + c16) * 64 + kt * 32 + qd * 8, 1.0f);
            acc[nt] = mfma16(a, b, acc[nt]);
        }
    }
    /* reduce ssum over qd lanes (bits 4,5): h for row 16w+c16 on every lane */
    ssum += __shfl_xor(ssum, 16);
    ssum += __shfl_xor(ssum, 32);
    const float h_red = 0.5f * ssum;
    const int row0 = 16 * w + 4 * qd;
    float h4[4];
    #pragma unroll
    for (int r = 0; r < 4; ++r) h4[r] = __shfl(h_red, 4 * qd + r);

    /* ---- chunk max ---- */
    float lmax = -1e30f;
    #pragma unroll
    for (int r = 0; r < 4; ++r) {
        #pragma unroll
        for (int nt = 0; nt < 8; ++nt) lmax = fmaxf(lmax, acc[nt][r] - h4[r]);
    }
    #pragma unroll
    for (int o = 1; o <= 32; o <<= 1) lmax = fmaxf(lmax, __shfl_xor(lmax, o));
    if (lane == 0) wred[w] = lmax;
    /* ---- colsumV partials (f32 exact) ---- */
    {
        const int d = t & 63, g = t >> 6;
        float s = 0.f;
        #pragma unroll
        for (int j = 0; j < 16; ++j) s += vb[(16 * g + j) * 64 + d];
        csum[g][d] = s;
    }
    /* ---- Vt[d][l] paired b32 (before barrier1; visible at MFMA2) ---- */
    #pragma unroll
    for (int rep = 0; rep < 8; ++rep) {
        int e2 = rep * 512 + t;
        int d = e2 & 63, l2 = e2 >> 6;
        unsigned a = f2bf(vb[(2 * l2) * 64 + d]);
        unsigned b = f2bf(vb[(2 * l2 + 1) * 64 + d]);
        *(unsigned*)&Vt[d * KSTR + 2 * l2] = a | (b << 16);
    }
    if (t < 128) Vt[64 * KSTR + t] = 0x3F80;      /* ones column -> z~ */
    __syncthreads();                               /* barrier 1: wred */
    float mc = wred[0];
    #pragma unroll
    for (int i = 1; i < 8; ++i) mc = fmaxf(mc, wred[i]);
    if (t == 0) partial[bx] = mc;

    /* ---- phi'_k -> PKt[m][l], packed b64 ---- */
    #pragma unroll
    for (int nt = 0; nt < 8; ++nt) {
        union { s16x4 v; unsigned short s[4]; } u;
        #pragma unroll
        for (int r = 0; r < 4; ++r) {
            float pk = __expf(acc[nt][r] - h4[r] - mc) * INVSQRT_M;
            u.s[r] = f2bf(pk);
        }
        *(s16x4*)&PKt[(16 * nt + c16) * KSTR + row0] = u.v;
    }
    __syncthreads();                               /* barrier 2: PKt ready */

    f32x4 acc2[5];
    #pragma unroll
    for (int nt = 0; nt < 5; ++nt) acc2[nt] = (f32x4){0.f, 0.f, 0.f, 0.f};
    #pragma unroll
    for (int kt = 0; kt < 4; ++kt) {
        bf16x8 a = *(const bf16x8*)&PKt[(16 * w + c16) * KSTR + kt * 32 + qd * 8];
        #pragma unroll
        for (int nt = 0; nt < 5; ++nt) {
            bf16x8 b = *(const bf16x8*)&Vt[(16 * nt + c16) * KSTR + kt * 32 + qd * 8];
            acc2[nt] = mfma16(a, b, acc2[nt]);
        }
    }
    float* sb = Sbuf + (size_t)bx * STATE_STRIDE;
    #pragma unroll
    for (int r = 0; r < 4; ++r) {
        #pragma unroll
        for (int nt = 0; nt < 4; ++nt)
            sb[(row0 + r) * 64 + 16 * nt + c16] = acc2[nt][r];
        if (c16 == 0) sb[8192 + row0 + r] = acc2[4][r];
    }
    if (t < 64) {
        float s = 0.f;
        #pragma unroll
        for (int g = 0; g < 8; ++g) s += csum[g][t];
        csumV[(size_t)bx * 64 + t] = s;
    }
}

// ---------------------------------------------------------------------------
__global__ void gmax_kernel(const float* __restrict__ partial, int n, float* __restrict__ gmax) {
    float m = -1e30f;
    for (int i = threadIdx.x; i < n; i += 256) m = fmaxf(m, partial[i]);
    #pragma unroll
    for (int o = 1; o <= 32; o <<= 1) m = fmaxf(m, __shfl_xor(m, o));
    __shared__ float w[4];
    if ((threadIdx.x & 63) == 0) w[threadIdx.x >> 6] = m;
    __syncthreads();
    if (threadIdx.x == 0) gmax[0] = fmaxf(fmaxf(w[0], w[1]), fmaxf(w[2], w[3]));
}

// ---------------------------------------------------------------------------
// prefix: exclusive prefix of  e^{m_c-gmax} S~_c + eps*colsumV.
// ILP rewrite: preload all 32 chunk values (independent loads), in-register
// scan, independent stores. No load-store serialization.
// ---------------------------------------------------------------------------
#define PBLK 33   /* ceil(8320/256) slices per (b,h) */
__global__ __launch_bounds__(256) void prefix_kernel(
    float* __restrict__ Sbuf, const float* __restrict__ csumV,
    const float* __restrict__ partial, const float* __restrict__ gmaxp) {
    const int bh = blockIdx.x / PBLK;
    const int e = (blockIdx.x % PBLK) * 256 + threadIdx.x;
    if (e >= STATE_STRIDE) return;
    const float gm = gmaxp[0];
    const int isZ = (e >= 8192);
    const int d = e & 63;
    const size_t base = (size_t)bh * Cq * STATE_STRIDE + e;

    float vals[Cq];
    #pragma unroll
    for (int c = 0; c < Cq; ++c) vals[c] = Sbuf[base + (size_t)c * STATE_STRIDE];

    float running = 0.f;
    #pragma unroll
    for (int c = 0; c < Cq; ++c) {
        const int cx = bh * Cq + c;
        float sc = __expf(partial[cx] - gm);
        float ep = isZ ? (EPS_PHI * 128.0f) : (EPS_PHI * csumV[(size_t)cx * 64 + d]);
        float v = sc * vals[c] + ep;
        Sbuf[base + (size_t)c * STATE_STRIDE] = running;
        running += v;
    }
}

// ---------------------------------------------------------------------------
// replay: proj (h in-register), phi, A_s = tril(PQ PK^T), out = [A_s|PQ].W.
// PQ and A_s never touch LDS: wave-private fragment transposes are done with
// __shfl (pull + select). LDS = PK (34.8K) + Wt (42.2K) = 77K -> 2 blocks/CU.
//
// Fragment algebra (16x16x32, A/B frag: lane&15 = row(A)/col(B), k at qd*8):
//  phi_q regs: lane(c16,qd) holds pqu[r][i]: PQ[16w+4qd+r][m=16(2i..)+c16] pairs,
//    perm-packed p = c16*8+nt.
//  bq[kt][j] = PQ[16w+c16][p=kt*32+qd*8+j]  -> src lane (4kt+qd)+16*(c16>>2),
//    slot r = c16&3 (shuffle all 4 r, select).
//  GEMM1 (swapped): a1[lt] = D[l=16lt+4qd+r][q=16w+c16], masked l<=q, packed
//    to asu[lt][2].
//  GEMM2 A-frag kt(0..3): A_s[16w+c16][l=kt*32+qd*8+j]:
//    j0..3 from lane c16+16*((2qd)&3), j4..7 from c16+16*((2qd+1)&3),
//    slot lt = 2kt+(qd>>1). kt(4..7): afrag = bq[kt-4].
// ---------------------------------------------------------------------------
__global__ __launch_bounds__(512, 4) void replay_kernel(
    const float* __restrict__ q, const float* __restrict__ kin,
    const float* __restrict__ vin, const float* __restrict__ omega,
    const float* __restrict__ gmaxp, const float* __restrict__ Sbuf,
    float* __restrict__ out) {
    __shared__ __align__(16) unsigned short PK[128 * KSTR];  /* [l][perm(m)] */
    __shared__ __align__(16) unsigned short Wt[80 * WSTR];   /* [d|wz][l;128+perm(m)] */
    const int t = threadIdx.x, w = t >> 6, lane = t & 63;
    const int c16 = lane & 15, qd = lane >> 4;
    const int bx = blockIdx.x;
    const size_t rowbase = (size_t)(bx >> 5) * Nq + (size_t)(bx & 31) * Lq;
    const float* qb = q + rowbase * 64;
    const float* kb = kin + rowbase * 64;
    const float* vb = vin + rowbase * 64;
    const float gmax = gmaxp[0];
    const int row0 = 16 * w + 4 * qd;
    const int arow = 16 * w + c16;

    /* ---- proj_q + proj_k fused; h from the k loads ---- */
    f32x4 accq[8], acck[8];
    float ssum = 0.f;
    #pragma unroll
    for (int nt = 0; nt < 8; ++nt) {
        accq[nt] = (f32x4){0.f, 0.f, 0.f, 0.f};
        acck[nt] = (f32x4){0.f, 0.f, 0.f, 0.f};
    }
    #pragma unroll
    for (int kt = 0; kt < 2; ++kt) {
        bf16x8 aq = gfrag(qb + (size_t)arow * 64 + kt * 32 + qd * 8, SCALE);
        bf16x8 ak = gfrag_h(kb + (size_t)arow * 64 + kt * 32 + qd * 8, &ssum);
        #pragma unroll
        for (int nt = 0; nt < 8; ++nt) {
            bf16x8 b = gfrag(omega + (size_t)(16 * nt + c16) * 64 + kt * 32 + qd * 8, 1.0f);
            accq[nt] = mfma16(aq, b, accq[nt]);
            acck[nt] = mfma16(ak, b, acck[nt]);
        }
    }
    ssum += __shfl_xor(ssum, 16);
    ssum += __shfl_xor(ssum, 32);
    const float h_red = 0.5f * ssum;

    /* ---- phi_q into registers (perm-packed pairs) ---- */
    unsigned pqu[4][4];
    #pragma unroll
    for (int r = 0; r < 4; ++r) {
        float mx = accq[0][r];
        #pragma unroll
        for (int nt = 1; nt < 8; ++nt) mx = fmaxf(mx, accq[nt][r]);
        mx = fmaxf(mx, __shfl_xor(mx, 1));
        mx = fmaxf(mx, __shfl_xor(mx, 2));
        mx = fmaxf(mx, __shfl_xor(mx, 4));
        mx = fmaxf(mx, __shfl_xor(mx, 8));
        #pragma unroll
        for (int i = 0; i < 4; ++i) {
            float lo = __expf(accq[2 * i][r]     - mx) * INVSQRT_M + EPS_PHI;
            float hi = __expf(accq[2 * i + 1][r] - mx) * INVSQRT_M + EPS_PHI;
            pqu[r][i] = (unsigned)f2bf(lo) | ((unsigned)f2bf(hi) << 16);
        }
    }
    /* ---- build bq[kt] (PQ A/B-frag for row arow) via shuffles ---- */
    bf16x8 bq[4];
    {
        const int rsel = c16 & 3;
        #pragma unroll
        for (int kt = 0; kt < 4; ++kt) {
            const int src = 4 * kt + qd + ((c16 >> 2) << 4);
            union { bf16x8 v; unsigned u[4]; } tt;
            #pragma unroll
            for (int i = 0; i < 4; ++i) {
                unsigned v0 = __shfl(pqu[0][i], src);
                unsigned v1 = __shfl(pqu[1][i], src);
                unsigned v2 = __shfl(pqu[2][i], src);
                unsigned v3 = __shfl(pqu[3][i], src);
                unsigned s01 = (rsel & 1) ? v1 : v0;
                unsigned s23 = (rsel & 1) ? v3 : v2;
                tt.u[i] = (rsel & 2) ? s23 : s01;
            }
            bq[kt] = tt.v;
        }
    }
    /* ---- phi_k -> PK[l][perm(m)], b128 packed ---- */
    #pragma unroll
    for (int r = 0; r < 4; ++r) {
        float h = __shfl(h_red, 4 * qd + r);
        union { bf16x8 v; unsigned short s[8]; } u;
        #pragma unroll
        for (int nt = 0; nt < 8; ++nt)
            u.s[nt] = f2bf(__expf(acck[nt][r] - h - gmax) * INVSQRT_M + EPS_PHI);
        *(bf16x8*)&PK[(row0 + r) * KSTR + c16 * 8] = u.v;
    }
    /* ---- Wt fill: V^T paired b32; S_in at perm cols; z row ---- */
    const float* sb = Sbuf + (size_t)bx * STATE_STRIDE;
    #pragma unroll
    for (int rep = 0; rep < 8; ++rep) {
        int e2 = rep * 512 + t;
        int d = e2 & 63, l2 = e2 >> 6;
        unsigned a = f2bf(vb[(2 * l2) * 64 + d]);
        unsigned b = f2bf(vb[(2 * l2 + 1) * 64 + d]);
        *(unsigned*)&Wt[d * WSTR + 2 * l2] = a | (b << 16);
    }
    #pragma unroll
    for (int rep = 0; rep < 16; ++rep) {
        int e = rep * 512 + t;
        int m = e >> 6, d = e & 63;
        Wt[d * WSTR + 128 + PERM(m)] = f2bf(sb[e]);
    }
    if (t < 128)      Wt[64 * WSTR + t] = 0x3F80;
    else if (t < 256) Wt[64 * WSTR + 128 + PERM(t - 128)] = f2bf(sb[8192 + (t - 128)]);
    __syncthreads();   /* the ONE barrier: PK + Wt visibility */

    /* ---- GEMM1 swapped: a1[lt] = D[l][q-tile], keep all 8 ---- */
    f32x4 a1[8];
    #pragma unroll
    for (int lt = 0; lt < 8; ++lt) {
        a1[lt] = (f32x4){0.f, 0.f, 0.f, 0.f};
        #pragma unroll
        for (int kt = 0; kt < 4; ++kt) {
            bf16x8 a = *(const bf16x8*)&PK[(16 * lt + c16) * KSTR + kt * 32 + qd * 8];
            a1[lt] = mfma16(a, bq[kt], a1[lt]);
        }
    }
    /* ---- causal mask + pack A_s to registers ---- */
    unsigned asu[8][2];
    #pragma unroll
    for (int lt = 0; lt < 8; ++lt) {
        const int lbase = 16 * lt + 4 * qd;
        float m0 = (lbase + 0 <= arow) ? a1[lt][0] : 0.f;
        float m1 = (lbase + 1 <= arow) ? a1[lt][1] : 0.f;
        float m2 = (lbase + 2 <= arow) ? a1[lt][2] : 0.f;
        float m3 = (lbase + 3 <= arow) ? a1[lt][3] : 0.f;
        asu[lt][0] = (unsigned)f2bf(m0) | ((unsigned)f2bf(m1) << 16);
        asu[lt][1] = (unsigned)f2bf(m2) | ((unsigned)f2bf(m3) << 16);
    }
    /* ---- GEMM2: [num|den] = [A_s|PQ] . Wt^T ---- */
    f32x4 acc2[5];
    #pragma unroll
    for (int nt = 0; nt < 5; ++nt) acc2[nt] = (f32x4){0.f, 0.f, 0.f, 0.f};
    {
        const int src0 = c16 + ((2 * qd) & 3) * 16;
        const int src1 = c16 + ((2 * qd + 1) & 3) * 16;
        const int hsel = qd >> 1;
        #pragma unroll
        for (int kt = 0; kt < 4; ++kt) {
            union { bf16x8 v; unsigned u[4]; } af;
            unsigned a00 = __shfl(asu[2 * kt][0], src0), a10 = __shfl(asu[2 * kt + 1][0], src0);
            unsigned a01 = __shfl(asu[2 * kt][1], src0), a11 = __shfl(asu[2 * kt + 1][1], src0);
            af.u[0] = hsel ? a10 : a00;
            af.u[1] = hsel ? a11 : a01;
            unsigned b00 = __shfl(asu[2 * kt][0], src1), b10 = __shfl(asu[2 * kt + 1][0], src1);
            unsigned b01 = __shfl(asu[2 * kt][1], src1), b11 = __shfl(asu[2 * kt + 1][1], src1);
            af.u[2] = hsel ? b10 : b00;
            af.u[3] = hsel ? b11 : b01;
            #pragma unroll
            for (int nt = 0; nt < 5; ++nt) {
                bf16x8 b = *(const bf16x8*)&Wt[(16 * nt + c16) * WSTR + kt * 32 + qd * 8];
                acc2[nt] = mfma16(af.v, b, acc2[nt]);
            }
        }
        #pragma unroll
        for (int kt = 4; kt < 8; ++kt) {
            #pragma unroll
            for (int nt = 0; nt < 5; ++nt) {
                bf16x8 b = *(const bf16x8*)&Wt[(16 * nt + c16) * WSTR + kt * 32 + qd * 8];
                acc2[nt] = mfma16(bq[kt - 4], b, acc2[nt]);
            }
        }
    }
    /* ---- epilogue: den broadcast from c16==0 holder lane ---- */
    #pragma unroll
    for (int r = 0; r < 4; ++r) {
        float den = __shfl(acc2[4][r], lane & 48) + EPS_DEN;
        float rd = 1.0f / den;
        #pragma unroll
        for (int nt = 0; nt < 4; ++nt)
            out[(rowbase + row0 + r) * 64 + 16 * nt + c16] = acc2[nt][r] * rd;
    }
}

// ---------------------------------------------------------------------------
extern "C" void kernel_launch(void* const* d_in, const int* in_sizes, int n_in,
                              void* d_out, int out_size, void* d_ws, size_t ws_size,
                              hipStream_t stream) {
    const float* q     = (const float*)d_in[0];
    const float* k     = (const float*)d_in[1];
    const float* v     = (const float*)d_in[2];
    const float* omega = (const float*)d_in[3];
    float* out = (float*)d_out;
    float* ws  = (float*)d_ws;

    const int nChunks = Bq * Hq * Cq;            /* 2048 */
    float* partial = ws;                         /* 2048 */
    float* gmax    = partial + nChunks;          /* 1 (+pad) */
    float* Sbuf    = gmax + 16;                  /* 2048 * 8320 = 68.2 MB */
    float* csumV   = Sbuf + (size_t)nChunks * STATE_STRIDE; /* 2048*64 */

    chunkstate_kernel<<<nChunks, 512, 0, stream>>>(k, v, omega, partial, Sbuf, csumV);
    gmax_kernel<<<1, 256, 0, stream>>>(partial, nChunks, gmax);
    prefix_kernel<<<64 * PBLK, 256, 0, stream>>>(Sbuf, csumV, partial, gmax);
    replay_kernel<<<nChunks, 512, 0, stream>>>(q, k, v, omega, gmax, Sbuf, out);
}